// Round 10
// baseline (9757.652 us; speedup 1.0000x reference)
//
#include <hip/hip_runtime.h>
#include <hip/hip_fp16.h>
#include <stdint.h>

#define NB 32
#define NT 2048
#define ND 256
#define NU 256

typedef _Float16 f16x2 __attribute__((ext_vector_type(2)));

__device__ __forceinline__ float fdot2u(uint32_t a, uint32_t b, float c) {
#if __has_builtin(__builtin_amdgcn_fdot2)
  return __builtin_amdgcn_fdot2(__builtin_bit_cast(f16x2, a),
                                __builtin_bit_cast(f16x2, b), c, false);
#else
  f16x2 av = __builtin_bit_cast(f16x2, a);
  f16x2 bv = __builtin_bit_cast(f16x2, b);
  return c + (float)av.x * (float)bv.x + (float)av.y * (float)bv.y;
#endif
}

__device__ __forceinline__ uint32_t packh2(float lo, float hi) {
  f16x2 p;
  p.x = (_Float16)lo;
  p.y = (_Float16)hi;
  return __builtin_bit_cast(uint32_t, p);
}

__device__ __forceinline__ float rcp_fast(float x) { return __builtin_amdgcn_rcpf(x); }
__device__ __forceinline__ float sigmoid_fast(float x) {
  return rcp_fast(1.f + __expf(-x));
}
__device__ __forceinline__ float tanh_fast(float x) {
  return 1.f - 2.f * rcp_fast(1.f + __expf(2.f * x));
}

// Dynamic LDS layout (bytes). Rec path: Wh image + control buffers.
// GEMM path reuses the arena as SGemm (51200 B).
#define LDS_WH 0          // u32[128][256], k2-major: Wh2[k2*256+u]
#define LDS_H2 131072     // u32[128]  packed h pairs
#define LDS_RH2 131584    // u32[128]  packed r*h pairs
#define LDS_PSH 132096    // float[256] role1's h_hat partial
#define LDS_HBUF 133120   // float[256] h (f32)
#define LDS_TOTAL 134144

extern __shared__ char smdyn[];

struct SGemm {
  float a[64][132];
  float b[64][68];
};

// Named-var asm weight block: w0..w31 (128 VGPRs). All defs are UNTIED "=v"
// (tied "+v" on 128-bit tuples is unsupported: "tied indirect register
// inputs", R8/R9). Ordering of re-issue vs consumption is enforced by a
// sched_barrier(0) immediately before the issue block; asm volatile stmts
// are mutually ordered, and data deps pin everything else.
#define WDECL \
  uint4 w0, w1, w2, w3, w4, w5, w6, w7, w8, w9, w10, w11, w12, w13, w14, w15, \
      w16, w17, w18, w19, w20, w21, w22, w23, w24, w25, w26, w27, w28, w29,   \
      w30, w31;

#define WL(i, P, OFF) \
  asm volatile("global_load_dwordx4 %0, %1, off" OFF : "=v"(w##i) : "v"(P));

#define WGRP(i0, i1, i2, i3, P) \
  WL(i0, P, "") WL(i1, P, " offset:16") WL(i2, P, " offset:32") WL(i3, P, " offset:48")

#define WISSUE \
  WGRP(0, 1, 2, 3, pA) WGRP(4, 5, 6, 7, pB) WGRP(8, 9, 10, 11, pC) \
  WGRP(12, 13, 14, 15, pD) WGRP(16, 17, 18, 19, pE) WGRP(20, 21, 22, 23, pF) \
  WGRP(24, 25, 26, 27, pG) WGRP(28, 29, 30, 31, pH)

#define DOTA(i)                                     \
  {                                                 \
    const uint4 hv = *(const uint4*)&h2L[(i) * 4];  \
    a0 = fdot2u(w##i.x, hv.x, a0);                  \
    a1 = fdot2u(w##i.y, hv.y, a1);                  \
    a2 = fdot2u(w##i.z, hv.z, a2);                  \
    a3 = fdot2u(w##i.w, hv.w, a3);                  \
  }
#define DOTA8(i0, i1, i2, i3, i4, i5, i6, i7) \
  DOTA(i0) DOTA(i1) DOTA(i2) DOTA(i3) DOTA(i4) DOTA(i5) DOTA(i6) DOTA(i7)

// blocks [0, recCnt): recurrence, one batch each. blocks [recCnt,..): x-proj GEMM.
__global__ __launch_bounds__(512)
__attribute__((amdgpu_waves_per_eu(2, 2)))
void gru_combined(
    const float* __restrict__ x, const float* __restrict__ Wz,
    const float* __restrict__ Wr, const float* __restrict__ Wh,
    const uint32_t* __restrict__ Wp, float* __restrict__ hstate,
    float* __restrict__ out, const float* __restrict__ Gsrc,
    float* __restrict__ Gdst, int t0r, int t0g, int recCnt, int chunkT) {
  const int tid = threadIdx.x;

  if ((int)blockIdx.x < recCnt) {
    // ---------------- recurrence ----------------
    const int b = blockIdx.x;
    const int u = tid & 255;
    const int role = tid >> 8;  // 0: z-gate + blend ; 1: r-gate

    uint32_t* WhL = (uint32_t*)(smdyn + LDS_WH);
    uint32_t* h2L = (uint32_t*)(smdyn + LDS_H2);
    uint32_t* rh2L = (uint32_t*)(smdyn + LDS_RH2);
    float* pshL = (float*)(smdyn + LDS_PSH);
    float* hbufL = (float*)(smdyn + LDS_HBUF);

    // streamed gate column (Wz role0 / Wr role1), 8 group pointers
    const uint4* colb = ((const uint4*)Wp) + (size_t)role * 8192 + (u << 2);
    const uint4* pA = colb;
    const uint4* pB = colb + 1024;
    const uint4* pC = colb + 2048;
    const uint4* pD = colb + 3072;
    const uint4* pE = colb + 4096;
    const uint4* pF = colb + 5120;
    const uint4* pG = colb + 6144;
    const uint4* pH = colb + 7168;
    WDECL
    WISSUE  // prologue stream (lands before first consume via loop-top wait)

    // Wh -> LDS (128 KB), tracked loads (complete before first barrier)
    {
      const uint4* WpH4 = ((const uint4*)Wp) + 16384;
      uint4* WhL4 = (uint4*)(smdyn + LDS_WH);
#pragma unroll
      for (int i = 0; i < 16; ++i) WhL4[tid + i * 512] = WpH4[tid + i * 512];
    }
    float hprev = hstate[b * NU + u];
    if (tid < NU) hbufL[tid] = hprev;
    __syncthreads();
    if (tid < 128) h2L[tid] = packh2(hbufL[2 * tid], hbufL[2 * tid + 1]);
    __syncthreads();

    const char* gp = (const char*)(Gsrc + (size_t)b * NU + u) +
                     (role == 0 ? 0 : (size_t)NB * NU * 4);
    const size_t gstride = (size_t)3 * NB * NU * 4;
    float* outp = out + ((size_t)b * NT + t0r) * NU + u;

    for (int tt = 0; tt < chunkT; ++tt) {
      // weights issued last iteration (or prologue) must have landed
      asm volatile("s_waitcnt vmcnt(0)" ::: "memory");
      __builtin_amdgcn_sched_barrier(0);
      // issue this step's G loads (untracked)
      float gA, gB = 0.f;
      asm volatile("global_load_dword %0, %1, off" : "=v"(gA) : "v"(gp));
      if (role == 0)
        asm volatile("global_load_dword %0, %1, off"
                     : "=v"(gB)
                     : "v"(gp + 2 * (size_t)NB * NU * 4));
      // phase A: full-K gate dot from pinned regs + h2 broadcast
      float a0 = 0.f, a1 = 0.f, a2 = 0.f, a3 = 0.f;
      DOTA8(0, 1, 2, 3, 4, 5, 6, 7)
      DOTA8(8, 9, 10, 11, 12, 13, 14, 15)
      DOTA8(16, 17, 18, 19, 20, 21, 22, 23)
      DOTA8(24, 25, 26, 27, 28, 29, 30, 31)
      // G landed (weights fully consumed above; only G outstanding)
      asm volatile("s_waitcnt vmcnt(0)" ::: "memory");
      __builtin_amdgcn_sched_barrier(0);
      const float ssum = ((a0 + a1) + (a2 + a3)) + gA;
      float zval = 0.f;
      if (role == 0) {
        zval = sigmoid_fast(ssum);
      } else {
        const float rr = sigmoid_fast(ssum);
        const float rh = rr * hprev;
        const float rh1 = __shfl_down(rh, 1);
        if ((u & 1) == 0) rh2L[u >> 1] = packh2(rh, rh1);
      }
      // re-issue NEXT step's stream. sched_barrier pins the new defs BELOW
      // the dots above (old values' last use), keeping it single-buffered;
      // the loads then stay in flight across the bare barriers below.
      __builtin_amdgcn_sched_barrier(0);
      WISSUE
      __syncthreads();  // b1: rh2 ready
      // phase B: h_hat partial over this role's K-half, Wh from LDS
      float c0 = 0.f, c1 = 0.f, c2 = 0.f, c3 = 0.f;
#pragma unroll
      for (int j = 0; j < 64; j += 4) {
        const int k2 = (role << 6) + j;
        const uint4 r4 = *(const uint4*)&rh2L[k2];  // broadcast
        c0 = fdot2u(WhL[(k2 + 0) * 256 + u], r4.x, c0);
        c1 = fdot2u(WhL[(k2 + 1) * 256 + u], r4.y, c1);
        c2 = fdot2u(WhL[(k2 + 2) * 256 + u], r4.z, c2);
        c3 = fdot2u(WhL[(k2 + 3) * 256 + u], r4.w, c3);
      }
      const float cown = (c0 + c1) + (c2 + c3);
      if (role == 1) pshL[u] = cown;
      __syncthreads();  // b2: psh ready
      if (role == 0) {
        const float hh = tanh_fast(gB + cown + pshL[u]);
        const float hn = zval * hprev + (1.f - zval) * hh;
        hprev = hn;
        asm volatile("global_store_dword %0, %1, off" ::"v"(outp), "v"(hn));
        hbufL[u] = hn;
        const float hn1 = __shfl_down(hn, 1);
        if ((u & 1) == 0) h2L[u >> 1] = packh2(hn, hn1);
      }
      outp += NU;
      gp += gstride;
      __syncthreads();  // b3: h ready for next step
      if (role == 1) hprev = hbufL[u];
    }
    if (role == 0) hstate[b * NU + u] = hprev;
    asm volatile("s_waitcnt vmcnt(0)" ::: "memory");  // drain asm stores/loads

  } else if (Gdst != nullptr) {
    // ---------------- x-projection GEMM for next chunk ----------------
    SGemm& smg = *(SGemm*)smdyn;
    const int gg = (int)blockIdx.x - recCnt;
    const int mtile = gg / 12;
    const int ntile = gg - mtile * 12;
    const int g = ntile >> 2;
    const int u0 = (ntile & 3) * 64;
    const float* Wg = (g == 0) ? Wz : ((g == 1) ? Wr : Wh);
    const int ty = tid >> 4;
    const int tx = tid & 15;
    const int mbase = mtile * 128;
    float acc[4][4] = {{0.f}};

    for (int kk = 0; kk < 4; ++kk) {
      const int k0 = kk * 64;
      __syncthreads();
      {
        const int ml = tid & 127;
        const int kq = tid >> 7;
        const int m = mbase + ml;
        const int bb = m / chunkT;
        const int ttm = m - bb * chunkT;
        const float* xp = x + ((size_t)bb * NT + t0g + ttm) * ND + k0 + kq * 16;
#pragma unroll
        for (int v = 0; v < 4; ++v) {
          float4 xv = ((const float4*)xp)[v];
          smg.a[kq * 16 + v * 4 + 0][ml] = xv.x;
          smg.a[kq * 16 + v * 4 + 1][ml] = xv.y;
          smg.a[kq * 16 + v * 4 + 2][ml] = xv.z;
          smg.a[kq * 16 + v * 4 + 3][ml] = xv.w;
        }
      }
      {
        const int nl = (tid & 15) * 4;
        const int kr = tid >> 4;
#pragma unroll
        for (int s2 = 0; s2 < 2; ++s2) {
          const int krow = kr + s2 * 32;
          float4 wvv = *(const float4*)&Wg[(size_t)(k0 + krow) * NU + u0 + nl];
          *(float4*)&smg.b[krow][nl] = wvv;
        }
      }
      __syncthreads();
#pragma unroll 8
      for (int k = 0; k < 64; ++k) {
        const float4 av = *(const float4*)&smg.a[k][ty * 4];
        const float4 bv = *(const float4*)&smg.b[k][tx * 4];
        acc[0][0] += av.x * bv.x; acc[0][1] += av.x * bv.y; acc[0][2] += av.x * bv.z; acc[0][3] += av.x * bv.w;
        acc[1][0] += av.y * bv.x; acc[1][1] += av.y * bv.y; acc[1][2] += av.y * bv.z; acc[1][3] += av.y * bv.w;
        acc[2][0] += av.z * bv.x; acc[2][1] += av.z * bv.y; acc[2][2] += av.z * bv.z; acc[2][3] += av.z * bv.w;
        acc[3][0] += av.w * bv.x; acc[3][1] += av.w * bv.y; acc[3][2] += av.w * bv.z; acc[3][3] += av.w * bv.w;
      }
    }
#pragma unroll
    for (int i = 0; i < 4; ++i) {
      const int m = mbase + ty * 4 + i;
      const int bb = m / chunkT;
      const int ttm = m - bb * chunkT;
      float4 val;
      val.x = acc[i][0]; val.y = acc[i][1]; val.z = acc[i][2]; val.w = acc[i][3];
      *(float4*)&Gdst[((size_t)(ttm * 3 + g) * NB + bb) * NU + u0 + tx * 4] = val;
    }
  }
}

// one-time prep: pack recurrent weight rows [D, D+U) as f16 pairs.
// S region (streamed Wz/Wr): u32 idx = g*32768 + j4*4096 + u*16 + c*4 + p,
//   k0 = (j4*4+c)*8 + 2p. H region (Wh for LDS): idx = 65536 + k2*256 + u.
__global__ void gru_prep(const float* __restrict__ Wz, const float* __restrict__ Wr,
                         const float* __restrict__ Wh, uint32_t* __restrict__ Wp,
                         float* __restrict__ hstate) {
  const int idx = blockIdx.x * 256 + threadIdx.x;
  if (idx < 65536) {
    const int p = idx & 3;
    const int c = (idx >> 2) & 3;
    const int u = (idx >> 4) & 255;
    const int j4 = (idx >> 12) & 7;
    const int g = (idx >> 15) & 1;
    const float* Wg = (g == 0) ? Wz : Wr;
    const int k0 = (j4 * 4 + c) * 8 + 2 * p;
    Wp[idx] = packh2(Wg[(size_t)(ND + k0) * NU + u], Wg[(size_t)(ND + k0 + 1) * NU + u]);
  } else if (idx < 98304) {
    const int r = idx - 65536;
    const int u = r & 255;
    const int k2 = r >> 8;
    Wp[idx] = packh2(Wh[(size_t)(ND + 2 * k2) * NU + u],
                     Wh[(size_t)(ND + 2 * k2 + 1) * NU + u]);
  } else if (idx - 98304 < NB * NU) {
    hstate[idx - 98304] = 0.f;
  }
}

extern "C" void kernel_launch(void* const* d_in, const int* in_sizes, int n_in,
                              void* d_out, int out_size, void* d_ws, size_t ws_size,
                              hipStream_t stream) {
  (void)in_sizes; (void)n_in; (void)out_size;
  const float* x = (const float*)d_in[0];
  const float* Wz = (const float*)d_in[1];
  const float* Wr = (const float*)d_in[2];
  const float* Wh = (const float*)d_in[3];
  float* out = (float*)d_out;

  hipFuncSetAttribute((const void*)gru_combined,
                      hipFuncAttributeMaxDynamicSharedMemorySize, LDS_TOTAL);

  int ct = 8;
  const int cands[6] = {256, 128, 64, 32, 16, 8};
  for (int i = 0; i < 6; ++i) {
    size_t need = 2ull * cands[i] * 3 * NB * NU * 4 + (1u << 20);
    if (need <= ws_size) { ct = cands[i]; break; }
  }
  const int nch = NT / ct;
  const size_t chunkBytes = (size_t)ct * 3 * NB * NU * 4;

  char* wsb = (char*)d_ws;
  float* G0 = (float*)wsb;
  float* G1 = (float*)(wsb + chunkBytes);
  uint32_t* Wp = (uint32_t*)(wsb + 2 * chunkBytes);
  float* hstate = (float*)(wsb + 2 * chunkBytes + 98304ull * 4);

  gru_prep<<<416, 256, 0, stream>>>(Wz, Wr, Wh, Wp, hstate);

  // chunk 0 x-projection only
  gru_combined<<<3 * ct, 512, LDS_TOTAL, stream>>>(
      x, Wz, Wr, Wh, Wp, hstate, out, nullptr, G0, 0, 0, 0, ct);
  for (int k = 0; k < nch; ++k) {
    float* Gsrc = (k & 1) ? G1 : G0;
    float* Gdst = (k & 1) ? G0 : G1;
    const int gemmOn = (k + 1 < nch) ? 1 : 0;
    gru_combined<<<32 + (gemmOn ? 3 * ct : 0), 512, LDS_TOTAL, stream>>>(
        x, Wz, Wr, Wh, Wp, hstate, out, Gsrc, gemmOn ? Gdst : nullptr,
        k * ct, (k + 1) * ct, 32, ct);
  }
}